// Round 15
// baseline (133.715 us; speedup 1.0000x reference)
//
#include <hip/hip_runtime.h>
#include <stdint.h>

#define BATCH 16
#define NQ 2000
#define NC 80
#define NG 100
#define MAX_ITERS 1000
#define MAXC 96
#define QT 32
#define TILES 63                     // ceil(2000/32)
#define K1_TILEB (BATCH * TILES)     // 1008 tile blocks
#define K1_BLOCKS (K1_TILEB + 400)   // + 400 taskB blocks
#define K3_BS 1024
#define NW3 16
#define NCAND 8
#define LSTRIDE 9
#define QINF 0x7fffffff
#define SQINF 0x7fff

// output layout (floats)
#define OFF_SEL 0
#define OFF_GTI (BATCH * NQ)                 // 32000
#define OFF_MQ (2 * BATCH * NQ)              // 64000
#define OFF_M (2 * BATCH * NQ + BATCH * NG)  // 65600

// ws layout (bytes) — fast path
#define WS_COST  0                          // float[16][100][2000] = 12,800,000
#define WS_LISTS 12800000                   // float[16*100*9] = 57,600
#define WS_CAND8 12857600                   // float2[16][100][63][8] = 6,451,200
#define WS_MW    19308800                   // uint32[16][4][NQ] = 512,000 (planes)
#define WS_MIT   19820800                   // int16[16][NQ] = 64,000
#define WS_CIDX  19884800                   // int16[16][NQ] = 64,000
#define WS_CROW  19948800                   // float[16][MAXC][NG] = 614,400
#define WS_SCAL  20563200                   // int[16][8] = 512
#define WS_NEED  20563712

// exact replay of the reference's sequential in-place +1e5 adds
__device__ __forceinline__ float fmut(float c, int k) {
    for (int i = 0; i < k; ++i) c += 100000.0f;
    return c;
}

__device__ __forceinline__ bool lexlt(float v1, int i1, float v2, int i2) {
    return (v1 < v2) | ((v1 == v2) & (i1 < i2));
}

#define CE(vv, ii, a, b) do { \
    bool t_ = lexlt(vv[b], ii[b], vv[a], ii[a]); \
    float lo_ = t_ ? vv[b] : vv[a]; float hi_ = t_ ? vv[a] : vv[b]; \
    int loi_ = t_ ? ii[b] : ii[a]; int hii_ = t_ ? ii[a] : ii[b]; \
    vv[a] = lo_; vv[b] = hi_; ii[a] = loi_; ii[b] = hii_; \
} while (0)

#define INS8(vv, ii, val, idx) do { float v_ = (val); int i_ = (idx); \
    bool ins_ = lexlt(v_, i_, vv[7], ii[7]); \
    vv[7] = ins_ ? v_ : vv[7]; ii[7] = ins_ ? i_ : ii[7]; \
    CE(vv, ii, 6, 7); CE(vv, ii, 5, 6); CE(vv, ii, 4, 5); CE(vv, ii, 3, 4); \
    CE(vv, ii, 2, 3); CE(vv, ii, 1, 2); CE(vv, ii, 0, 1); \
} while (0)

#define MERGE8(va, ia) do { \
    for (int off_ = 1; off_ < 64; off_ <<= 1) { \
        float bv_[8]; int bi_[8]; \
        _Pragma("unroll") \
        for (int j_ = 0; j_ < 8; ++j_) { bv_[j_] = __shfl_xor(va[j_], off_, 64); bi_[j_] = __shfl_xor(ia[j_], off_, 64); } \
        float mv_[8]; int mi_[8]; \
        _Pragma("unroll") \
        for (int j_ = 0; j_ < 8; ++j_) { \
            bool t_ = lexlt(bv_[7 - j_], bi_[7 - j_], va[j_], ia[j_]); \
            mv_[j_] = t_ ? bv_[7 - j_] : va[j_]; mi_[j_] = t_ ? bi_[7 - j_] : ia[j_]; \
        } \
        _Pragma("unroll") \
        for (int d_ = 4; d_ >= 1; d_ >>= 1) { \
            _Pragma("unroll") \
            for (int i_ = 0; i_ < 8; ++i_) { \
                if ((i_ & d_) == 0) CE(mv_, mi_, i_, (i_ | d_)); \
            } \
        } \
        _Pragma("unroll") \
        for (int j_ = 0; j_ < 8; ++j_) { va[j_] = mv_[j_]; ia[j_] = mi_[j_]; } \
    } \
} while (0)

// taskB body: top-5 IoU -> dyn_k for wave-index w (one wave per (b,g))
__device__ __forceinline__ void dynk_wave(int w, int lane,
                                          const float* __restrict__ pred_boxes,
                                          const float* __restrict__ gt_boxes,
                                          const float* __restrict__ img_sz,
                                          float* __restrict__ lists) {
    int b = w / NG, g = w - b * NG;
    const float i0 = img_sz[b * 4 + 0], i1 = img_sz[b * 4 + 1];
    const float i2 = img_sz[b * 4 + 2], i3 = img_sz[b * 4 + 3];
    const float4 gt = *reinterpret_cast<const float4*>(gt_boxes + (b * NG + g) * 4);
    float GX1 = (gt.x - 0.5f * gt.z) * i0, GY1 = (gt.y - 0.5f * gt.w) * i1;
    float GX2 = (gt.x + 0.5f * gt.z) * i2, GY2 = (gt.y + 0.5f * gt.w) * i3;
    float GA = (GX2 - GX1) * (GY2 - GY1);

    const float* pbox = pred_boxes + (size_t)b * NQ * 4;
    float tv[5]; int ti[5];
#pragma unroll
    for (int j = 0; j < 5; ++j) { tv[j] = INFINITY; ti[j] = QINF; }

    for (int q = lane; q < NQ; q += 64) {
        const float4 pb = *reinterpret_cast<const float4*>(pbox + q * 4);
        float x1 = (pb.x - 0.5f * pb.z) * i0, y1 = (pb.y - 0.5f * pb.w) * i1;
        float x2 = (pb.x + 0.5f * pb.z) * i2, y2 = (pb.y + 0.5f * pb.w) * i3;
        float aA = (x2 - x1) * (y2 - y1);
        float lx = fmaxf(x1, GX1), ly = fmaxf(y1, GY1);
        float rx = fminf(x2, GX2), ry = fminf(y2, GY2);
        float iw = fmaxf(rx - lx, 0.0f), ih = fmaxf(ry - ly, 0.0f);
        float inter = iw * ih;
        float uni = aA + GA - inter;
        float niou = -(inter / uni);
        bool ins = lexlt(niou, q, tv[4], ti[4]);
        tv[4] = ins ? niou : tv[4]; ti[4] = ins ? q : ti[4];
        CE(tv, ti, 3, 4); CE(tv, ti, 2, 3); CE(tv, ti, 1, 2); CE(tv, ti, 0, 1);
    }

#pragma unroll
    for (int off = 1; off < 64; off <<= 1) {
        float bv[5]; int bi[5];
#pragma unroll
        for (int j = 0; j < 5; ++j) { bv[j] = __shfl_xor(tv[j], off, 64); bi[j] = __shfl_xor(ti[j], off, 64); }
        float mv[8]; int mi[8];
#pragma unroll
        for (int j = 0; j < 3; ++j) { mv[j] = tv[j]; mi[j] = ti[j]; }
#pragma unroll
        for (int j = 3; j < 5; ++j) {
            bool t = lexlt(bv[7 - j], bi[7 - j], tv[j], ti[j]);
            mv[j] = t ? bv[7 - j] : tv[j]; mi[j] = t ? bi[7 - j] : ti[j];
        }
#pragma unroll
        for (int j = 5; j < 8; ++j) { mv[j] = bv[7 - j]; mi[j] = bi[7 - j]; }
#pragma unroll
        for (int d = 4; d >= 1; d >>= 1) {
#pragma unroll
            for (int i = 0; i < 8; ++i) {
                if ((i & d) == 0) CE(mv, mi, i, (i | d));
            }
        }
#pragma unroll
        for (int j = 0; j < 5; ++j) { tv[j] = mv[j]; ti[j] = mi[j]; }
    }

    if (lane == 0) {
        float s = -((((tv[0] + tv[1]) + tv[2]) + tv[3]) + tv[4]);
        int k = (int)s;
        if (k < 1) k = 1;
        lists[(size_t)w * LSTRIDE] = (float)k;
    }
}

// =================== K1: fg + cost + rowargmin + per-tile bottom-8 | taskB dynk ===================
__global__ __launch_bounds__(256) void fgcost_kernel(
    const float* __restrict__ logits, const float* __restrict__ pred_boxes,
    const float* __restrict__ gt_boxes, const int* __restrict__ labels,
    const float* __restrict__ img_sz, float* __restrict__ costT_all,
    float* __restrict__ rowamin, float* __restrict__ lists,
    float2* __restrict__ cand8) {
    const int tid = threadIdx.x;

    if (blockIdx.x >= K1_TILEB) {
        int w = (blockIdx.x - K1_TILEB) * 4 + (tid >> 6);
        dynk_wave(w, tid & 63, pred_boxes, gt_boxes, img_sz, lists);
        return;
    }

    const int b = blockIdx.x / TILES;
    const int tile = blockIdx.x - b * TILES;
    const int q0 = tile * QT;

    __shared__ float ct[QT][NG + 1];
    __shared__ float s_rx1[NG], s_ry1[NG], s_rx2[NG], s_ry2[NG];
    __shared__ float s_clx[NG], s_chx[NG], s_cly[NG], s_chy[NG];
    __shared__ float s_gx1[NG], s_gy1[NG], s_gx2[NG], s_gy2[NG];
    __shared__ float s_d1[NG], s_d2[NG], s_d3[NG], s_d4[NG];
    __shared__ float s_ga[NG];
    __shared__ int s_lab[NG];
    __shared__ float pbx[QT][11];
    __shared__ unsigned fgm[QT];

    const float i0 = img_sz[b * 4 + 0], i1 = img_sz[b * 4 + 1];
    const float i2 = img_sz[b * 4 + 2], i3 = img_sz[b * 4 + 3];

    if (tid < NG) {
        const float4 gt = *reinterpret_cast<const float4*>(gt_boxes + (b * NG + tid) * 4);
        float GX1 = (gt.x - 0.5f * gt.z) * i0, GY1 = (gt.y - 0.5f * gt.w) * i1;
        float GX2 = (gt.x + 0.5f * gt.z) * i2, GY2 = (gt.y + 0.5f * gt.w) * i3;
        float tcx = (GX1 + GX2) * 0.5f, tcy = (GY1 + GY2) * 0.5f;
        float tw = GX2 - GX1, th = GY2 - GY1;
        float X1 = tcx - 0.5f * tw, Y1 = tcy - 0.5f * th;
        float X2 = tcx + 0.5f * tw, Y2 = tcy + 0.5f * th;
        float w_ = X2 - X1, h_ = Y2 - Y1;
        s_rx1[tid] = X1; s_ry1[tid] = Y1; s_rx2[tid] = X2; s_ry2[tid] = Y2;
        s_clx[tid] = tcx - 2.5f * w_; s_chx[tid] = tcx + 2.5f * w_;
        s_cly[tid] = tcy - 2.5f * h_; s_chy[tid] = tcy + 2.5f * h_;
        s_gx1[tid] = GX1; s_gy1[tid] = GY1; s_gx2[tid] = GX2; s_gy2[tid] = GY2;
        s_d1[tid] = GX1 / i0; s_d2[tid] = GY1 / i1; s_d3[tid] = GX2 / i2; s_d4[tid] = GY2 / i3;
        s_ga[tid] = (GX2 - GX1) * (GY2 - GY1);
        s_lab[tid] = labels[b * NG + tid];
    }
    if (tid < QT) {
        fgm[tid] = 0;
        int q = q0 + tid;
        if (q < NQ) {
            const float4 pb = *reinterpret_cast<const float4*>(pred_boxes + (size_t)(b * NQ + q) * 4);
            float x1 = (pb.x - 0.5f * pb.z) * i0, y1 = (pb.y - 0.5f * pb.w) * i1;
            float x2 = (pb.x + 0.5f * pb.z) * i2, y2 = (pb.y + 0.5f * pb.w) * i3;
            pbx[tid][0] = x1; pbx[tid][1] = y1; pbx[tid][2] = x2; pbx[tid][3] = y2;
            pbx[tid][4] = (x1 + x2) * 0.5f; pbx[tid][5] = (y1 + y2) * 0.5f;
            pbx[tid][6] = x1 / i0; pbx[tid][7] = y1 / i1; pbx[tid][8] = x2 / i2; pbx[tid][9] = y2 / i3;
            pbx[tid][10] = (x2 - x1) * (y2 - y1);
        }
    }
    __syncthreads();

    {
        int ql = tid & 31, part = tid >> 5;
        if (q0 + ql < NQ) {
            float ax = pbx[ql][4], ay = pbx[ql][5];
            int gbeg = part * 13;
            int gend = gbeg + 13 < NG ? gbeg + 13 : NG;
            bool any = false;
            for (int g = gbeg; g < gend; ++g) {
                bool in_box = (ax > s_rx1[g]) && (ax < s_rx2[g]) && (ay > s_ry1[g]) && (ay < s_ry2[g]);
                bool in_ctr = (ax > s_clx[g]) && (ax < s_chx[g]) && (ay > s_cly[g]) && (ay < s_chy[g]);
                any = any || in_box || in_ctr;
            }
            if (any) atomicOr(&fgm[ql], 1u);
        }
    }
    __syncthreads();

    for (int idx = tid; idx < QT * NG; idx += 256) {
        int ql = idx / NG, g = idx - ql * NG;
        int q = q0 + ql;
        if (q < NQ) {
            float x1 = pbx[ql][0], y1 = pbx[ql][1], x2 = pbx[ql][2], y2 = pbx[ql][3];
            float ax = pbx[ql][4], ay = pbx[ql][5];
            bool in_box = (ax > s_rx1[g]) && (ax < s_rx2[g]) && (ay > s_ry1[g]) && (ay < s_ry2[g]);
            bool in_ctr = (ax > s_clx[g]) && (ax < s_chx[g]) && (ay > s_cly[g]) && (ay < s_chy[g]);
            bool in_bc = in_box && in_ctr;
            bool fgb = fgm[ql] != 0;

            float lg = logits[(size_t)(b * NQ + q) * NC + s_lab[g]];
            float p = 1.0f / (1.0f + expf(-lg));
            float neg = 0.75f * (p * p) * (-logf(1.0f - p + 1e-8f));
            float pos = 0.25f * ((1.0f - p) * (1.0f - p)) * (-logf(p + 1e-8f));
            float cc = pos - neg;

            float cb = fabsf(pbx[ql][6] - s_d1[g]);
            cb = cb + fabsf(pbx[ql][7] - s_d2[g]);
            cb = cb + fabsf(pbx[ql][8] - s_d3[g]);
            cb = cb + fabsf(pbx[ql][9] - s_d4[g]);

            float aA = pbx[ql][10];
            float GX1 = s_gx1[g], GY1 = s_gy1[g], GX2 = s_gx2[g], GY2 = s_gy2[g];
            float lx = fmaxf(x1, GX1), ly = fmaxf(y1, GY1);
            float rx = fminf(x2, GX2), ry = fminf(y2, GY2);
            float iw = fmaxf(rx - lx, 0.0f), ih = fmaxf(ry - ly, 0.0f);
            float inter = iw * ih;
            float uni = aA + s_ga[g] - inter;
            float iou = inter / uni;
            float hx1 = fminf(x1, GX1), hy1 = fminf(y1, GY1);
            float hx2 = fmaxf(x2, GX2), hy2 = fmaxf(y2, GY2);
            float hw = fmaxf(hx2 - hx1, 0.0f), hh = fmaxf(hy2 - hy1, 0.0f);
            float harea = hw * hh;
            float giou = iou - (harea - uni) / harea;

            float cost = 5.0f * cb;
            cost = cost + 2.0f * cc;
            cost = cost + 2.0f * (-giou);
            cost = cost + (in_bc ? 0.0f : 100.0f);
            cost = cost + (fgb ? 0.0f : 10000.0f);
            ct[ql][g] = cost;
        }
    }
    __syncthreads();

    float* dst = costT_all + (size_t)b * NQ * NG;
    for (int idx = tid; idx < QT * NG; idx += 256) {
        int g = idx >> 5, ql = idx & 31;
        int q = q0 + ql;
        if (q < NQ) dst[(size_t)g * NQ + q] = ct[ql][g];
    }
    if (tid < QT && q0 + tid < NQ) {
        float mv = ct[tid][0]; int mg = 0;
        for (int g = 1; g < NG; ++g) { float v = ct[tid][g]; if (v < mv) { mv = v; mg = g; } }
        rowamin[b * NQ + q0 + tid] = (float)mg;
    }
    // per-tile bottom-8 per column (fast path): column read stride 101 -> conflict-free
    if (cand8 != nullptr && tid < NG) {
        int g = tid;
        float va[8]; int ia[8];
#pragma unroll
        for (int j = 0; j < 8; ++j) { va[j] = INFINITY; ia[j] = QINF; }
        for (int ql = 0; ql < QT; ++ql) {
            int q = q0 + ql;
            float v = (q < NQ) ? ct[ql][g] : INFINITY;
            int qi = (q < NQ) ? q : QINF;
            INS8(va, ia, v, qi);
        }
        float2* o = cand8 + ((size_t)(b * NG + g) * TILES + tile) * 8;
#pragma unroll
        for (int j = 0; j < 8; ++j)
            o[j] = make_float2(va[j], (ia[j] == QINF) ? 3.0e9f : (float)ia[j]);
    }
}

// =================== K2 (mono path only): taskA bottom-8 | taskB dynk ===================
__global__ __launch_bounds__(256) void init_kernel(const float* __restrict__ pred_boxes,
                                                   const float* __restrict__ gt_boxes,
                                                   const float* __restrict__ img_sz,
                                                   const float* __restrict__ costT_all,
                                                   float* __restrict__ lists) {
    const int tid = threadIdx.x;
    const int wid = tid >> 6, lane = tid & 63;

    if (blockIdx.x < 400) {
        int w = blockIdx.x * 4 + wid;
        int b = w / NG, g = w - b * NG;
        const float* col = costT_all + (size_t)b * NQ * NG + (size_t)g * NQ;

        float va[8]; int ia[8];
#pragma unroll
        for (int j = 0; j < 8; ++j) { va[j] = INFINITY; ia[j] = QINF; }
        for (int q = lane; q < NQ; q += 64) {
            float v = col[q];
            INS8(va, ia, v, q);
        }
        MERGE8(va, ia);
        if (lane == 0) {
            float* o = lists + (size_t)w * LSTRIDE;
            o[1] = (float)ia[0]; o[2] = (float)ia[1]; o[3] = (float)ia[2]; o[4] = (float)ia[3];
            o[5] = (float)ia[4]; o[6] = (float)ia[5]; o[7] = (float)ia[6]; o[8] = (float)ia[7];
        }
        return;
    }

    int w = (blockIdx.x - 400) * 4 + wid;
    dynk_wave(w, lane, pred_boxes, gt_boxes, img_sz, lists);
}

// =================== K3: match_main — merge candidates + prologue + loop, dump state ===================
__global__ __launch_bounds__(K3_BS) void match_main(const float* __restrict__ lists,
                                                    const float* __restrict__ rowamin_all,
                                                    const float* __restrict__ costT_all,
                                                    char* __restrict__ ws) {
    const int b = blockIdx.x;
    const int tid = threadIdx.x;
    const int wave = tid >> 6;
    const int lane = tid & 63;

    __shared__ uint32_t Mw[4][NQ];         // 32 KB (plane layout)
    __shared__ float crow[MAXC][NG + 1];   // 38.8 KB
    __shared__ int m_it[NQ];               // 8 KB
    __shared__ int16_t c16[NQ];            // 4 KB
    __shared__ int16_t cand[NG][NCAND];    // 1.6 KB
    __shared__ int crowq[MAXC];
    __shared__ int colcnt[NG];
    __shared__ int needscan[NG];
    __shared__ int touched[128];
    __shared__ int nconf0, nscan, ntq, persist;

    uint32_t* MwG = (uint32_t*)(ws + WS_MW) + (size_t)b * 4 * NQ;
    int16_t* mitG = (int16_t*)(ws + WS_MIT) + (size_t)b * NQ;
    int16_t* cidxG = (int16_t*)(ws + WS_CIDX) + (size_t)b * NQ;
    float* crowG = (float*)(ws + WS_CROW) + (size_t)b * MAXC * NG;
    int* scalG = (int*)(ws + WS_SCAL) + b * 8;
    const float2* cand8 = (const float2*)(ws + WS_CAND8);
    const float* costT = costT_all + (size_t)b * NQ * NG;
    const float* rowamin_b = rowamin_all + b * NQ;

    if (tid == 0) { nconf0 = 0; nscan = 0; ntq = 0; persist = 0; }
    for (int q = tid; q < NQ; q += K3_BS) {
        Mw[0][q] = 0; Mw[1][q] = 0; Mw[2][q] = 0; Mw[3][q] = 0;
        c16[q] = -1; m_it[q] = QINF;
    }
    __syncthreads();

    // merge per-tile candidates -> global sorted bottom-8 per column (one wave per column)
    for (int g = wave; g < NG; g += NW3) {
        const float2* cnd = cand8 + (size_t)(b * NG + g) * TILES * 8;
        float va[8]; int ia[8];
#pragma unroll
        for (int j = 0; j < 8; ++j) { va[j] = INFINITY; ia[j] = QINF; }
        for (int i = lane; i < TILES * 8; i += 64) {
            float2 p = cnd[i];
            int qi = (p.y > 2.0e9f) ? QINF : (int)p.y;
            INS8(va, ia, p.x, qi);
        }
        MERGE8(va, ia);
        if (lane == 0) {
#pragma unroll
            for (int j = 0; j < NCAND; ++j)
                cand[g][j] = (ia[j] >= 32767) ? (int16_t)SQINF : (int16_t)ia[j];
        }
    }
    __syncthreads();

    if (tid < NG) {
        int k = (int)lists[(size_t)(b * NG + tid) * LSTRIDE];
        int word = tid >> 5;
        uint32_t bit = 1u << (tid & 31);
        for (int j = 0; j < 5; ++j)
            if (j < k) atomicOr(&Mw[word][(int)cand[tid][j]], bit);
        colcnt[tid] = k;
    }
    __syncthreads();

    // conflict0 pass
    for (int q = tid; q < NQ; q += K3_BS) {
        uint32_t w0 = Mw[0][q], w1 = Mw[1][q], w2 = Mw[2][q], w3 = Mw[3][q];
        int pc = __popc(w0) + __popc(w1) + __popc(w2) + __popc(w3);
        if (pc > 1) {
            int slot = atomicAdd(&nconf0, 1);
            int c = (slot < MAXC) ? slot : -1;
            c16[q] = (c >= 0) ? (int16_t)c : (int16_t)-2;
            m_it[q] = -1;
            if (c >= 0) crowq[c] = q;
            int mg = (int)rowamin_b[q];
            uint32_t words[4] = {w0, w1, w2, w3};
            for (int w = 0; w < 4; ++w) {
                uint32_t word = words[w];
                while (word) {
                    int bp = __ffs(word) - 1;
                    word &= word - 1;
                    atomicSub(&colcnt[w * 32 + bp], 1);
                }
                Mw[w][q] = 0;
            }
            Mw[mg >> 5][q] = 1u << (mg & 31);
            atomicAdd(&colcnt[mg], 1);
        } else if (pc == 1) {
            m_it[q] = -1;
        }
    }
    __syncthreads();

    const int nc0 = nconf0;
    const int ncached = (nc0 < MAXC) ? nc0 : MAXC;
    const bool hasOvf = nc0 > MAXC;
    for (int i = tid; i < ncached * NG; i += K3_BS) {
        int c = i / NG, g = i - c * NG;
        crow[c][g] = costT[(size_t)g * NQ + crowq[c]];
    }
    __syncthreads();

    int unm = __syncthreads_or(tid < NG && colcnt[tid] == 0);
    int L = 0;

    for (int it = 0; it < MAX_ITERS; ++it) {
        if (!unm) break;
        L = it + 1;

        for (int i = tid; i < ncached * NG; i += K3_BS) {
            int c = i / NG, g = i - c * NG;
            crow[c][g] += 100000.0f;
        }
        if (tid < NG && colcnt[tid] == 0) {
            int g = tid;
            int win = -1;
            for (int j = 0; j < NCAND; ++j) {
                int qi = cand[g][j];
                if (qi != SQINF && m_it[qi] >= it) { win = qi; break; }
            }
            if (win >= 0) {
                atomicOr(&Mw[g >> 5][win], 1u << (g & 31));
                atomicMin(&m_it[win], it);
                colcnt[g] = 1;
                touched[atomicAdd(&ntq, 1)] = win;
            } else {
                needscan[atomicAdd(&nscan, 1)] = g;
            }
        }
        __syncthreads();  // B2

        int ns = nscan;
        if (ns > 0) {
            for (int s = wave; s < ns; s += NW3) {
                int g = needscan[s];
                const float* col = costT + (size_t)g * NQ;
                float mv = INFINITY; int mi = QINF;
                for (int q = lane; q < NQ; q += 64) {
                    if (m_it[q] >= it) {
                        float v = col[q];
                        if (v < mv || (v == mv && q < mi)) { mv = v; mi = q; }
                    }
                }
                for (int off = 1; off < 64; off <<= 1) {
                    float ov = __shfl_xor(mv, off); int oi = __shfl_xor(mi, off);
                    if (ov < mv || (ov == mv && oi < mi)) { mv = ov; mi = oi; }
                }
                if (mi == QINF) {
                    for (int q = lane; q < NQ; q += 64) {
                        int nq = it - m_it[q]; if (nq < 0) nq = 0;
                        float v = fmut(col[q], nq);
                        if (v < mv || (v == mv && q < mi)) { mv = v; mi = q; }
                    }
                    for (int off = 1; off < 64; off <<= 1) {
                        float ov = __shfl_xor(mv, off); int oi = __shfl_xor(mi, off);
                        if (ov < mv || (ov == mv && oi < mi)) { mv = ov; mi = oi; }
                    }
                }
                if (lane == 0) {
                    atomicOr(&Mw[g >> 5][mi], 1u << (g & 31));
                    atomicMin(&m_it[mi], it);
                    colcnt[g] = 1;
                    touched[atomicAdd(&ntq, 1)] = mi;
                }
            }
            __syncthreads();  // B2b
        }

        int myconf = (tid == 0 && persist) ? 1 : 0;
        int nt = ntq;
        for (int s = tid; s < nt; s += K3_BS) {
            int q = touched[s];
            int pc = __popc(Mw[0][q]) + __popc(Mw[1][q]) + __popc(Mw[2][q]) + __popc(Mw[3][q]);
            if (pc > 1) {
                myconf = 1;
                if (c16[q] == -1) persist = 1;
            }
        }
        int hc = __syncthreads_or(myconf);
        if (!hc) break;

        if (tid == 0) { ntq = 0; nscan = 0; }
        for (int c = tid; c < ncached; c += K3_BS) {
            int q = crowq[c];
            float mv = crow[c][0]; int mg = 0;
            for (int g = 1; g < NG; ++g) { float v = crow[c][g]; if (v < mv) { mv = v; mg = g; } }
            int keepw = mg >> 5;
            uint32_t keepb = 1u << (mg & 31);
            for (int w = 0; w < 4; ++w) {
                uint32_t word = Mw[w][q];
                uint32_t keep = (w == keepw) ? keepb : 0u;
                uint32_t toclear = word & ~keep;
                while (toclear) {
                    int bp = __ffs(toclear) - 1;
                    toclear &= toclear - 1;
                    atomicSub(&colcnt[w * 32 + bp], 1);
                }
                if (keep && !(word & keep)) atomicAdd(&colcnt[mg], 1);
                Mw[w][q] = keep;
            }
        }
        if (hasOvf) {
            for (int q = tid; q < NQ; q += K3_BS) {
                if (c16[q] != -2) continue;
                int k = it + 1;
                float mv = fmut(costT[q], k); int mg = 0;
                for (int g = 1; g < NG; ++g) {
                    float v = fmut(costT[(size_t)g * NQ + q], k);
                    if (v < mv) { mv = v; mg = g; }
                }
                int keepw = mg >> 5;
                uint32_t keepb = 1u << (mg & 31);
                for (int w = 0; w < 4; ++w) {
                    uint32_t word = Mw[w][q];
                    uint32_t keep = (w == keepw) ? keepb : 0u;
                    uint32_t toclear = word & ~keep;
                    while (toclear) {
                        int bp = __ffs(toclear) - 1;
                        toclear &= toclear - 1;
                        atomicSub(&colcnt[w * 32 + bp], 1);
                    }
                    if (keep && !(word & keep)) atomicAdd(&colcnt[mg], 1);
                    Mw[w][q] = keep;
                }
            }
        }
        __syncthreads();  // B3
        unm = __syncthreads_or(tid < NG && colcnt[tid] == 0);
    }

    // dump state
    uint32_t* MwF = &Mw[0][0];
    for (int i = tid; i < 4 * NQ; i += K3_BS) MwG[i] = MwF[i];
    for (int q = tid; q < NQ; q += K3_BS) {
        int v = m_it[q];
        mitG[q] = (v > 32000) ? (int16_t)SQINF : (int16_t)v;
        cidxG[q] = c16[q];
    }
    for (int i = tid; i < ncached * NG; i += K3_BS) crowG[i] = crow[i / NG][i - (i / NG) * NG];
    if (tid == 0) { scalG[0] = nc0; scalG[1] = L; }
}

// =================== K4: finish_ex — matched_qid | sel/gti | M expand ===================
__global__ __launch_bounds__(256) void finish_ex(const char* __restrict__ ws,
                                                 const float* __restrict__ costT_all,
                                                 float* __restrict__ out) {
    const int tid = threadIdx.x;
    const int blk = blockIdx.x;

    if (blk < 400) {
        int w = blk * 4 + (tid >> 6);
        int lane = tid & 63;
        int b = w / NG, g = w - b * NG;
        const int* scalG = (const int*)(ws + WS_SCAL) + b * 8;
        const int L = scalG[1];
        const uint32_t* MwP = (const uint32_t*)(ws + WS_MW) + (size_t)b * 4 * NQ + (size_t)(g >> 5) * NQ;
        const int16_t* mitG = (const int16_t*)(ws + WS_MIT) + (size_t)b * NQ;
        const int16_t* cidxG = (const int16_t*)(ws + WS_CIDX) + (size_t)b * NQ;
        const float* crowG = (const float*)(ws + WS_CROW) + (size_t)b * MAXC * NG;
        const float* col = costT_all + (size_t)b * NQ * NG + (size_t)g * NQ;
        const uint32_t bit = 1u << (g & 31);

        float mv = INFINITY; int mi = QINF;
        for (int q = lane; q < NQ; q += 64) {
            float v = 1e30f;
            if (MwP[q] & bit) {
                int c = cidxG[q];
                if (c >= 0) v = crowG[c * NG + g];
                else {
                    int m = mitG[q];
                    int nq = (m == SQINF) ? 0 : (L - 1 - m);
                    if (nq < 0) nq = 0;
                    v = fmut(col[q], nq);
                }
            }
            if (v < mv || (v == mv && q < mi)) { mv = v; mi = q; }
        }
        for (int off = 1; off < 64; off <<= 1) {
            float ov = __shfl_xor(mv, off); int oi = __shfl_xor(mi, off);
            if (ov < mv || (ov == mv && oi < mi)) { mv = ov; mi = oi; }
        }
        if (lane == 0) out[OFF_MQ + b * NG + g] = (float)mi;
        return;
    }

    if (blk < 525) {
        int idx = (blk - 400) * 256 + tid;
        if (idx < BATCH * NQ) {
            int b = idx / NQ, q = idx - b * NQ;
            const uint32_t* MwG = (const uint32_t*)(ws + WS_MW) + (size_t)b * 4 * NQ;
            uint32_t w0 = MwG[q], w1 = MwG[NQ + q], w2 = MwG[2 * NQ + q], w3 = MwG[3 * NQ + q];
            out[OFF_SEL + idx] = (w0 | w1 | w2 | w3) ? 1.0f : 0.0f;
            int gi = 0;
            if (w0) gi = __ffs(w0) - 1;
            else if (w1) gi = 32 + __ffs(w1) - 1;
            else if (w2) gi = 64 + __ffs(w2) - 1;
            else if (w3) gi = 96 + __ffs(w3) - 1;
            out[OFF_GTI + idx] = (float)gi;
        }
        return;
    }

    const int e = blk - 525;
    const int b = e >> 3, j = e & 7;
    const int q0 = j * 250;
    __shared__ uint32_t msk[4][256];
    const uint32_t* MwG = (const uint32_t*)(ws + WS_MW) + (size_t)b * 4 * NQ;
    for (int i = tid; i < 1000; i += 256) {
        int w = i / 250, q = i - w * 250;
        msk[w][q] = MwG[w * NQ + q0 + q];
    }
    __syncthreads();
    float4* dst = reinterpret_cast<float4*>(out + OFF_M + (size_t)b * NQ * NG + (size_t)q0 * NG);
    for (int i = tid; i < 6250; i += 256) {
        int flat = i * 4;
        int ql = flat / NG;
        int g0 = flat - ql * NG;
        uint32_t w = msk[g0 >> 5][ql];
        int sh = g0 & 31;
        float4 v;
        v.x = ((w >> sh) & 1) ? 1.0f : 0.0f;
        v.y = ((w >> (sh + 1)) & 1) ? 1.0f : 0.0f;
        v.z = ((w >> (sh + 2)) & 1) ? 1.0f : 0.0f;
        v.w = ((w >> (sh + 3)) & 1) ? 1.0f : 0.0f;
        dst[i] = v;
    }
}

// =================== fallback: monolithic match (small-ws path) ===================
__global__ __launch_bounds__(K3_BS) void match_mono(const float* __restrict__ lists,
                                                    float* __restrict__ out) {
    const int b = blockIdx.x;
    const int tid = threadIdx.x;
    const int wave = tid >> 6;
    const int lane = tid & 63;

    __shared__ uint32_t Msh[NQ][4];
    __shared__ float crow[MAXC][NG + 1];
    __shared__ int m_it[NQ];
    __shared__ int16_t cidx[NQ];
    __shared__ int candq[NG][NCAND];
    __shared__ int crowq[MAXC];
    __shared__ int colcnt[NG];
    __shared__ int needscan[NG];
    __shared__ int touched[128];
    __shared__ int nconf0, nscan, ntq, persist;

    float* costT = out + OFF_M + (size_t)b * NQ * NG;
    float* selOut = out + OFF_SEL + b * NQ;
    float* gtiOut = out + OFF_GTI + b * NQ;
    const float* rowamin_b = out + OFF_GTI + b * NQ;
    float* mqOut = out + OFF_MQ + b * NG;

    if (tid == 0) { nconf0 = 0; nscan = 0; ntq = 0; persist = 0; }
    for (int q = tid; q < NQ; q += K3_BS) {
        Msh[q][0] = 0; Msh[q][1] = 0; Msh[q][2] = 0; Msh[q][3] = 0;
        cidx[q] = -1; m_it[q] = QINF;
    }
    __syncthreads();
    if (tid < NG) {
        const float* o = lists + (size_t)(b * NG + tid) * LSTRIDE;
        int k = (int)o[0];
        int word = tid >> 5;
        uint32_t bit = 1u << (tid & 31);
        for (int j = 0; j < NCAND; ++j) candq[tid][j] = (int)o[1 + j];
        for (int j = 0; j < 5; ++j)
            if (j < k) atomicOr(&Msh[candq[tid][j]][word], bit);
        colcnt[tid] = k;
    }
    __syncthreads();
    for (int q = tid; q < NQ; q += K3_BS) {
        uint4 m = *reinterpret_cast<const uint4*>(&Msh[q][0]);
        int pc = __popc(m.x) + __popc(m.y) + __popc(m.z) + __popc(m.w);
        if (pc > 1) {
            int slot = atomicAdd(&nconf0, 1);
            int c = (slot < MAXC) ? slot : -1;
            cidx[q] = (c >= 0) ? (int16_t)c : (int16_t)-2;
            m_it[q] = -1;
            if (c >= 0) crowq[c] = q;
            int mg = (int)rowamin_b[q];
            uint32_t words[4] = {m.x, m.y, m.z, m.w};
            for (int w = 0; w < 4; ++w) {
                uint32_t word = words[w];
                while (word) {
                    int bp = __ffs(word) - 1;
                    word &= word - 1;
                    atomicSub(&colcnt[w * 32 + bp], 1);
                }
                Msh[q][w] = 0;
            }
            Msh[q][mg >> 5] = 1u << (mg & 31);
            atomicAdd(&colcnt[mg], 1);
        } else if (pc == 1) {
            m_it[q] = -1;
        }
    }
    __syncthreads();
    const int ncached = (nconf0 < MAXC) ? nconf0 : MAXC;
    const bool hasOvf = nconf0 > MAXC;
    for (int i = tid; i < ncached * NG; i += K3_BS) {
        int c = i / NG, g = i - c * NG;
        crow[c][g] = costT[(size_t)g * NQ + crowq[c]];
    }
    __syncthreads();
    int unm = __syncthreads_or(tid < NG && colcnt[tid] == 0);
    int L = 0;
    for (int it = 0; it < MAX_ITERS; ++it) {
        if (!unm) break;
        L = it + 1;
        for (int i = tid; i < ncached * NG; i += K3_BS) {
            int c = i / NG, g = i - c * NG;
            crow[c][g] += 100000.0f;
        }
        if (tid < NG && colcnt[tid] == 0) {
            int g = tid;
            int win = -1;
            for (int j = 0; j < NCAND; ++j) {
                int qi = candq[g][j];
                if (qi != QINF && m_it[qi] >= it) { win = qi; break; }
            }
            if (win >= 0) {
                atomicOr(&Msh[win][g >> 5], 1u << (g & 31));
                atomicMin(&m_it[win], it);
                colcnt[g] = 1;
                touched[atomicAdd(&ntq, 1)] = win;
            } else {
                needscan[atomicAdd(&nscan, 1)] = g;
            }
        }
        __syncthreads();
        int ns = nscan;
        if (ns > 0) {
            for (int s = wave; s < ns; s += NW3) {
                int g = needscan[s];
                const float* col = costT + (size_t)g * NQ;
                float mv = INFINITY; int mi = QINF;
                for (int q = lane; q < NQ; q += 64) {
                    if (m_it[q] >= it) {
                        float v = col[q];
                        if (v < mv || (v == mv && q < mi)) { mv = v; mi = q; }
                    }
                }
                for (int off = 1; off < 64; off <<= 1) {
                    float ov = __shfl_xor(mv, off); int oi = __shfl_xor(mi, off);
                    if (ov < mv || (ov == mv && oi < mi)) { mv = ov; mi = oi; }
                }
                if (mi == QINF) {
                    for (int q = lane; q < NQ; q += 64) {
                        int nq = it - m_it[q]; if (nq < 0) nq = 0;
                        float v = fmut(col[q], nq);
                        if (v < mv || (v == mv && q < mi)) { mv = v; mi = q; }
                    }
                    for (int off = 1; off < 64; off <<= 1) {
                        float ov = __shfl_xor(mv, off); int oi = __shfl_xor(mi, off);
                        if (ov < mv || (ov == mv && oi < mi)) { mv = ov; mi = oi; }
                    }
                }
                if (lane == 0) {
                    atomicOr(&Msh[mi][g >> 5], 1u << (g & 31));
                    atomicMin(&m_it[mi], it);
                    colcnt[g] = 1;
                    touched[atomicAdd(&ntq, 1)] = mi;
                }
            }
            __syncthreads();
        }
        int myconf = (tid == 0 && persist) ? 1 : 0;
        int nt = ntq;
        for (int s = tid; s < nt; s += K3_BS) {
            int q = touched[s];
            uint4 m = *reinterpret_cast<const uint4*>(&Msh[q][0]);
            int pc = __popc(m.x) + __popc(m.y) + __popc(m.z) + __popc(m.w);
            if (pc > 1) {
                myconf = 1;
                if (cidx[q] == -1) persist = 1;
            }
        }
        int hc = __syncthreads_or(myconf);
        if (!hc) break;
        if (tid == 0) { ntq = 0; nscan = 0; }
        for (int c = tid; c < ncached; c += K3_BS) {
            int q = crowq[c];
            float mv = crow[c][0]; int mg = 0;
            for (int g = 1; g < NG; ++g) { float v = crow[c][g]; if (v < mv) { mv = v; mg = g; } }
            int keepw = mg >> 5;
            uint32_t keepb = 1u << (mg & 31);
            for (int w = 0; w < 4; ++w) {
                uint32_t word = Msh[q][w];
                uint32_t keep = (w == keepw) ? keepb : 0u;
                uint32_t toclear = word & ~keep;
                while (toclear) {
                    int bp = __ffs(toclear) - 1;
                    toclear &= toclear - 1;
                    atomicSub(&colcnt[w * 32 + bp], 1);
                }
                if (keep && !(word & keep)) atomicAdd(&colcnt[mg], 1);
                Msh[q][w] = keep;
            }
        }
        if (hasOvf) {
            for (int q = tid; q < NQ; q += K3_BS) {
                if (cidx[q] != -2) continue;
                int k = it + 1;
                float mv = fmut(costT[q], k); int mg = 0;
                for (int g = 1; g < NG; ++g) {
                    float v = fmut(costT[(size_t)g * NQ + q], k);
                    if (v < mv) { mv = v; mg = g; }
                }
                int keepw = mg >> 5;
                uint32_t keepb = 1u << (mg & 31);
                for (int w = 0; w < 4; ++w) {
                    uint32_t word = Msh[q][w];
                    uint32_t keep = (w == keepw) ? keepb : 0u;
                    uint32_t toclear = word & ~keep;
                    while (toclear) {
                        int bp = __ffs(toclear) - 1;
                        toclear &= toclear - 1;
                        atomicSub(&colcnt[w * 32 + bp], 1);
                    }
                    if (keep && !(word & keep)) atomicAdd(&colcnt[mg], 1);
                    Msh[q][w] = keep;
                }
            }
        }
        __syncthreads();
        unm = __syncthreads_or(tid < NG && colcnt[tid] == 0);
    }
    for (int g = wave; g < NG; g += NW3) {
        int word = g >> 5;
        uint32_t bit = 1u << (g & 31);
        const float* col = costT + (size_t)g * NQ;
        float mv = INFINITY; int mi = QINF;
        for (int q = lane; q < NQ; q += 64) {
            float v = 1e30f;
            if (Msh[q][word] & bit) {
                int c = cidx[q];
                if (c >= 0) v = crow[c][g];
                else {
                    int nq = L - 1 - m_it[q]; if (nq < 0) nq = 0;
                    v = fmut(col[q], nq);
                }
            }
            if (v < mv || (v == mv && q < mi)) { mv = v; mi = q; }
        }
        for (int off = 1; off < 64; off <<= 1) {
            float ov = __shfl_xor(mv, off); int oi = __shfl_xor(mi, off);
            if (ov < mv || (ov == mv && oi < mi)) { mv = ov; mi = oi; }
        }
        if (lane == 0) mqOut[g] = (float)mi;
    }
    for (int q = tid; q < NQ; q += K3_BS) {
        uint4 m = *reinterpret_cast<const uint4*>(&Msh[q][0]);
        selOut[q] = (m.x | m.y | m.z | m.w) ? 1.0f : 0.0f;
        int gi = 0;
        if (m.x) gi = __ffs(m.x) - 1;
        else if (m.y) gi = 32 + __ffs(m.y) - 1;
        else if (m.z) gi = 64 + __ffs(m.z) - 1;
        else if (m.w) gi = 96 + __ffs(m.w) - 1;
        gtiOut[q] = (float)gi;
    }
    __syncthreads();
    for (int i = tid; i < NQ * NG; i += K3_BS) {
        int q = i / NG;
        int g = i - q * NG;
        costT[i] = (Msh[q][g >> 5] & (1u << (g & 31))) ? 1.0f : 0.0f;
    }
}

extern "C" void kernel_launch(void* const* d_in, const int* in_sizes, int n_in,
                              void* d_out, int out_size, void* d_ws, size_t ws_size,
                              hipStream_t stream) {
    const float* logits = (const float*)d_in[0];
    const float* pboxes = (const float*)d_in[1];
    const float* gboxes = (const float*)d_in[2];
    const int* labels = (const int*)d_in[3];
    const float* img = (const float*)d_in[4];
    float* out = (float*)d_out;
    char* ws = (char*)d_ws;

    if (ws_size >= (size_t)WS_NEED) {
        float* costT = (float*)(ws + WS_COST);
        float* lists = (float*)(ws + WS_LISTS);
        float2* cand8 = (float2*)(ws + WS_CAND8);
        // K1: cost tiles + per-tile bottom-8 + rowargmin + overlapped taskB (dyn_k)
        fgcost_kernel<<<K1_BLOCKS, 256, 0, stream>>>(logits, pboxes, gboxes, labels, img,
                                                     costT, out + OFF_GTI, lists, cand8);
        // K2: serial matching loop (candidate merge in prologue)
        match_main<<<BATCH, K3_BS, 0, stream>>>(lists, out + OFF_GTI, costT, ws);
        // K3: wide epilogue + M expand
        finish_ex<<<653, 256, 0, stream>>>(ws, costT, out);
    } else {
        float* lists = (float*)ws;  // 57.6 KB
        fgcost_kernel<<<K1_TILEB, 256, 0, stream>>>(logits, pboxes, gboxes, labels, img,
                                                    out + OFF_M, out + OFF_GTI, lists, nullptr);
        init_kernel<<<800, 256, 0, stream>>>(pboxes, gboxes, img, out + OFF_M, lists);
        match_mono<<<BATCH, K3_BS, 0, stream>>>(lists, out);
    }
}

// Round 16
// 84.175 us; speedup vs baseline: 1.5885x; 1.5885x over previous
//
#include <hip/hip_runtime.h>
#include <stdint.h>

#define BATCH 16
#define NQ 2000
#define NC 80
#define NG 100
#define MAX_ITERS 1000
#define MAXC 96
#define QT 32
#define TILES 63                     // ceil(2000/32)
#define K1_TILEB (BATCH * TILES)     // 1008 tile blocks
#define K1_BLOCKS (K1_TILEB + 400)   // + 400 taskB blocks
#define K3_BS 1024
#define NW3 16
#define NCAND 8
#define LSTRIDE 9                    // k + 8 candidate indices
#define QINF 0x7fffffff
#define SQINF 0x7fff

// output layout (floats)
#define OFF_SEL 0
#define OFF_GTI (BATCH * NQ)                 // 32000
#define OFF_MQ (2 * BATCH * NQ)              // 64000
#define OFF_M (2 * BATCH * NQ + BATCH * NG)  // 65600

// ws layout (bytes) — fast path
#define WS_COST  0                          // float[16][100][2000] = 12,800,000
#define WS_LISTS 12800000                   // float[16*100*9] = 57,600
#define WS_MW    12864000                   // uint32[16][4][NQ] = 512,000 (planes)
#define WS_MIT   13376000                   // int16[16][NQ] = 64,000
#define WS_CIDX  13440000                   // int16[16][NQ] = 64,000
#define WS_CROW  13504000                   // float[16][MAXC][NG] = 614,400
#define WS_SCAL  14118400                   // int[16][8] = 512
#define WS_NEED  14118912

// exact replay of the reference's sequential in-place +1e5 adds
__device__ __forceinline__ float fmut(float c, int k) {
    for (int i = 0; i < k; ++i) c += 100000.0f;
    return c;
}

__device__ __forceinline__ bool lexlt(float v1, int i1, float v2, int i2) {
    return (v1 < v2) | ((v1 == v2) & (i1 < i2));
}

#define CE(vv, ii, a, b) do { \
    bool t_ = lexlt(vv[b], ii[b], vv[a], ii[a]); \
    float lo_ = t_ ? vv[b] : vv[a]; float hi_ = t_ ? vv[a] : vv[b]; \
    int loi_ = t_ ? ii[b] : ii[a]; int hii_ = t_ ? ii[a] : ii[b]; \
    vv[a] = lo_; vv[b] = hi_; ii[a] = loi_; ii[b] = hii_; \
} while (0)

#define INS8(vv, ii, val, idx) do { float v_ = (val); int i_ = (idx); \
    bool ins_ = lexlt(v_, i_, vv[7], ii[7]); \
    vv[7] = ins_ ? v_ : vv[7]; ii[7] = ins_ ? i_ : ii[7]; \
    CE(vv, ii, 6, 7); CE(vv, ii, 5, 6); CE(vv, ii, 4, 5); CE(vv, ii, 3, 4); \
    CE(vv, ii, 2, 3); CE(vv, ii, 1, 2); CE(vv, ii, 0, 1); \
} while (0)

#define MERGE8(va, ia) do { \
    for (int off_ = 1; off_ < 64; off_ <<= 1) { \
        float bv_[8]; int bi_[8]; \
        _Pragma("unroll") \
        for (int j_ = 0; j_ < 8; ++j_) { bv_[j_] = __shfl_xor(va[j_], off_, 64); bi_[j_] = __shfl_xor(ia[j_], off_, 64); } \
        float mv_[8]; int mi_[8]; \
        _Pragma("unroll") \
        for (int j_ = 0; j_ < 8; ++j_) { \
            bool t_ = lexlt(bv_[7 - j_], bi_[7 - j_], va[j_], ia[j_]); \
            mv_[j_] = t_ ? bv_[7 - j_] : va[j_]; mi_[j_] = t_ ? bi_[7 - j_] : ia[j_]; \
        } \
        _Pragma("unroll") \
        for (int d_ = 4; d_ >= 1; d_ >>= 1) { \
            _Pragma("unroll") \
            for (int i_ = 0; i_ < 8; ++i_) { \
                if ((i_ & d_) == 0) CE(mv_, mi_, i_, (i_ | d_)); \
            } \
        } \
        _Pragma("unroll") \
        for (int j_ = 0; j_ < 8; ++j_) { va[j_] = mv_[j_]; ia[j_] = mi_[j_]; } \
    } \
} while (0)

// taskB body: top-5 IoU -> dyn_k for wave-index w (one wave per (b,g))
__device__ __forceinline__ void dynk_wave(int w, int lane,
                                          const float* __restrict__ pred_boxes,
                                          const float* __restrict__ gt_boxes,
                                          const float* __restrict__ img_sz,
                                          float* __restrict__ lists) {
    int b = w / NG, g = w - b * NG;
    const float i0 = img_sz[b * 4 + 0], i1 = img_sz[b * 4 + 1];
    const float i2 = img_sz[b * 4 + 2], i3 = img_sz[b * 4 + 3];
    const float4 gt = *reinterpret_cast<const float4*>(gt_boxes + (b * NG + g) * 4);
    float GX1 = (gt.x - 0.5f * gt.z) * i0, GY1 = (gt.y - 0.5f * gt.w) * i1;
    float GX2 = (gt.x + 0.5f * gt.z) * i2, GY2 = (gt.y + 0.5f * gt.w) * i3;
    float GA = (GX2 - GX1) * (GY2 - GY1);

    const float* pbox = pred_boxes + (size_t)b * NQ * 4;
    float tv[5]; int ti[5];
#pragma unroll
    for (int j = 0; j < 5; ++j) { tv[j] = INFINITY; ti[j] = QINF; }

    for (int q = lane; q < NQ; q += 64) {
        const float4 pb = *reinterpret_cast<const float4*>(pbox + q * 4);
        float x1 = (pb.x - 0.5f * pb.z) * i0, y1 = (pb.y - 0.5f * pb.w) * i1;
        float x2 = (pb.x + 0.5f * pb.z) * i2, y2 = (pb.y + 0.5f * pb.w) * i3;
        float aA = (x2 - x1) * (y2 - y1);
        float lx = fmaxf(x1, GX1), ly = fmaxf(y1, GY1);
        float rx = fminf(x2, GX2), ry = fminf(y2, GY2);
        float iw = fmaxf(rx - lx, 0.0f), ih = fmaxf(ry - ly, 0.0f);
        float inter = iw * ih;
        float uni = aA + GA - inter;
        float niou = -(inter / uni);
        bool ins = lexlt(niou, q, tv[4], ti[4]);
        tv[4] = ins ? niou : tv[4]; ti[4] = ins ? q : ti[4];
        CE(tv, ti, 3, 4); CE(tv, ti, 2, 3); CE(tv, ti, 1, 2); CE(tv, ti, 0, 1);
    }

#pragma unroll
    for (int off = 1; off < 64; off <<= 1) {
        float bv[5]; int bi[5];
#pragma unroll
        for (int j = 0; j < 5; ++j) { bv[j] = __shfl_xor(tv[j], off, 64); bi[j] = __shfl_xor(ti[j], off, 64); }
        float mv[8]; int mi[8];
#pragma unroll
        for (int j = 0; j < 3; ++j) { mv[j] = tv[j]; mi[j] = ti[j]; }
#pragma unroll
        for (int j = 3; j < 5; ++j) {
            bool t = lexlt(bv[7 - j], bi[7 - j], tv[j], ti[j]);
            mv[j] = t ? bv[7 - j] : tv[j]; mi[j] = t ? bi[7 - j] : ti[j];
        }
#pragma unroll
        for (int j = 5; j < 8; ++j) { mv[j] = bv[7 - j]; mi[j] = bi[7 - j]; }
#pragma unroll
        for (int d = 4; d >= 1; d >>= 1) {
#pragma unroll
            for (int i = 0; i < 8; ++i) {
                if ((i & d) == 0) CE(mv, mi, i, (i | d));
            }
        }
#pragma unroll
        for (int j = 0; j < 5; ++j) { tv[j] = mv[j]; ti[j] = mi[j]; }
    }

    if (lane == 0) {
        float s = -((((tv[0] + tv[1]) + tv[2]) + tv[3]) + tv[4]);
        int k = (int)s;
        if (k < 1) k = 1;
        lists[(size_t)w * LSTRIDE] = (float)k;
    }
}

// =================== K1: fg + cost + rowargmin tiles | taskB dynk (blocks >= K1_TILEB) ===================
__global__ __launch_bounds__(256) void fgcost_kernel(
    const float* __restrict__ logits, const float* __restrict__ pred_boxes,
    const float* __restrict__ gt_boxes, const int* __restrict__ labels,
    const float* __restrict__ img_sz, float* __restrict__ costT_all,
    float* __restrict__ rowamin, float* __restrict__ lists) {
    const int tid = threadIdx.x;

    if (blockIdx.x >= K1_TILEB) {
        int w = (blockIdx.x - K1_TILEB) * 4 + (tid >> 6);
        dynk_wave(w, tid & 63, pred_boxes, gt_boxes, img_sz, lists);
        return;
    }

    const int b = blockIdx.x / TILES;
    const int tile = blockIdx.x - b * TILES;
    const int q0 = tile * QT;

    __shared__ float ct[QT][NG + 1];
    __shared__ float s_rx1[NG], s_ry1[NG], s_rx2[NG], s_ry2[NG];
    __shared__ float s_clx[NG], s_chx[NG], s_cly[NG], s_chy[NG];
    __shared__ float s_gx1[NG], s_gy1[NG], s_gx2[NG], s_gy2[NG];
    __shared__ float s_d1[NG], s_d2[NG], s_d3[NG], s_d4[NG];
    __shared__ float s_ga[NG];
    __shared__ int s_lab[NG];
    __shared__ float pbx[QT][11];
    __shared__ unsigned fgm[QT];

    const float i0 = img_sz[b * 4 + 0], i1 = img_sz[b * 4 + 1];
    const float i2 = img_sz[b * 4 + 2], i3 = img_sz[b * 4 + 3];

    if (tid < NG) {
        const float4 gt = *reinterpret_cast<const float4*>(gt_boxes + (b * NG + tid) * 4);
        float GX1 = (gt.x - 0.5f * gt.z) * i0, GY1 = (gt.y - 0.5f * gt.w) * i1;
        float GX2 = (gt.x + 0.5f * gt.z) * i2, GY2 = (gt.y + 0.5f * gt.w) * i3;
        float tcx = (GX1 + GX2) * 0.5f, tcy = (GY1 + GY2) * 0.5f;
        float tw = GX2 - GX1, th = GY2 - GY1;
        float X1 = tcx - 0.5f * tw, Y1 = tcy - 0.5f * th;
        float X2 = tcx + 0.5f * tw, Y2 = tcy + 0.5f * th;
        float w_ = X2 - X1, h_ = Y2 - Y1;
        s_rx1[tid] = X1; s_ry1[tid] = Y1; s_rx2[tid] = X2; s_ry2[tid] = Y2;
        s_clx[tid] = tcx - 2.5f * w_; s_chx[tid] = tcx + 2.5f * w_;
        s_cly[tid] = tcy - 2.5f * h_; s_chy[tid] = tcy + 2.5f * h_;
        s_gx1[tid] = GX1; s_gy1[tid] = GY1; s_gx2[tid] = GX2; s_gy2[tid] = GY2;
        s_d1[tid] = GX1 / i0; s_d2[tid] = GY1 / i1; s_d3[tid] = GX2 / i2; s_d4[tid] = GY2 / i3;
        s_ga[tid] = (GX2 - GX1) * (GY2 - GY1);
        s_lab[tid] = labels[b * NG + tid];
    }
    if (tid < QT) {
        fgm[tid] = 0;
        int q = q0 + tid;
        if (q < NQ) {
            const float4 pb = *reinterpret_cast<const float4*>(pred_boxes + (size_t)(b * NQ + q) * 4);
            float x1 = (pb.x - 0.5f * pb.z) * i0, y1 = (pb.y - 0.5f * pb.w) * i1;
            float x2 = (pb.x + 0.5f * pb.z) * i2, y2 = (pb.y + 0.5f * pb.w) * i3;
            pbx[tid][0] = x1; pbx[tid][1] = y1; pbx[tid][2] = x2; pbx[tid][3] = y2;
            pbx[tid][4] = (x1 + x2) * 0.5f; pbx[tid][5] = (y1 + y2) * 0.5f;
            pbx[tid][6] = x1 / i0; pbx[tid][7] = y1 / i1; pbx[tid][8] = x2 / i2; pbx[tid][9] = y2 / i3;
            pbx[tid][10] = (x2 - x1) * (y2 - y1);
        }
    }
    __syncthreads();

    {
        int ql = tid & 31, part = tid >> 5;
        if (q0 + ql < NQ) {
            float ax = pbx[ql][4], ay = pbx[ql][5];
            int gbeg = part * 13;
            int gend = gbeg + 13 < NG ? gbeg + 13 : NG;
            bool any = false;
            for (int g = gbeg; g < gend; ++g) {
                bool in_box = (ax > s_rx1[g]) && (ax < s_rx2[g]) && (ay > s_ry1[g]) && (ay < s_ry2[g]);
                bool in_ctr = (ax > s_clx[g]) && (ax < s_chx[g]) && (ay > s_cly[g]) && (ay < s_chy[g]);
                any = any || in_box || in_ctr;
            }
            if (any) atomicOr(&fgm[ql], 1u);
        }
    }
    __syncthreads();

    for (int idx = tid; idx < QT * NG; idx += 256) {
        int ql = idx / NG, g = idx - ql * NG;
        int q = q0 + ql;
        if (q < NQ) {
            float x1 = pbx[ql][0], y1 = pbx[ql][1], x2 = pbx[ql][2], y2 = pbx[ql][3];
            float ax = pbx[ql][4], ay = pbx[ql][5];
            bool in_box = (ax > s_rx1[g]) && (ax < s_rx2[g]) && (ay > s_ry1[g]) && (ay < s_ry2[g]);
            bool in_ctr = (ax > s_clx[g]) && (ax < s_chx[g]) && (ay > s_cly[g]) && (ay < s_chy[g]);
            bool in_bc = in_box && in_ctr;
            bool fgb = fgm[ql] != 0;

            float lg = logits[(size_t)(b * NQ + q) * NC + s_lab[g]];
            float p = 1.0f / (1.0f + expf(-lg));
            float neg = 0.75f * (p * p) * (-logf(1.0f - p + 1e-8f));
            float pos = 0.25f * ((1.0f - p) * (1.0f - p)) * (-logf(p + 1e-8f));
            float cc = pos - neg;

            float cb = fabsf(pbx[ql][6] - s_d1[g]);
            cb = cb + fabsf(pbx[ql][7] - s_d2[g]);
            cb = cb + fabsf(pbx[ql][8] - s_d3[g]);
            cb = cb + fabsf(pbx[ql][9] - s_d4[g]);

            float aA = pbx[ql][10];
            float GX1 = s_gx1[g], GY1 = s_gy1[g], GX2 = s_gx2[g], GY2 = s_gy2[g];
            float lx = fmaxf(x1, GX1), ly = fmaxf(y1, GY1);
            float rx = fminf(x2, GX2), ry = fminf(y2, GY2);
            float iw = fmaxf(rx - lx, 0.0f), ih = fmaxf(ry - ly, 0.0f);
            float inter = iw * ih;
            float uni = aA + s_ga[g] - inter;
            float iou = inter / uni;
            float hx1 = fminf(x1, GX1), hy1 = fminf(y1, GY1);
            float hx2 = fmaxf(x2, GX2), hy2 = fmaxf(y2, GY2);
            float hw = fmaxf(hx2 - hx1, 0.0f), hh = fmaxf(hy2 - hy1, 0.0f);
            float harea = hw * hh;
            float giou = iou - (harea - uni) / harea;

            float cost = 5.0f * cb;
            cost = cost + 2.0f * cc;
            cost = cost + 2.0f * (-giou);
            cost = cost + (in_bc ? 0.0f : 100.0f);
            cost = cost + (fgb ? 0.0f : 10000.0f);
            ct[ql][g] = cost;
        }
    }
    __syncthreads();

    float* dst = costT_all + (size_t)b * NQ * NG;
    for (int idx = tid; idx < QT * NG; idx += 256) {
        int g = idx >> 5, ql = idx & 31;
        int q = q0 + ql;
        if (q < NQ) dst[(size_t)g * NQ + q] = ct[ql][g];
    }
    if (tid < QT && q0 + tid < NQ) {
        float mv = ct[tid][0]; int mg = 0;
        for (int g = 1; g < NG; ++g) { float v = ct[tid][g]; if (v < mv) { mv = v; mg = g; } }
        rowamin[b * NQ + q0 + tid] = (float)mg;
    }
}

// =================== K2: taskA bottom-8 (blocks 0..399) | taskB dynk (400..799, mono path only) ===================
__global__ __launch_bounds__(256) void init_kernel(const float* __restrict__ pred_boxes,
                                                   const float* __restrict__ gt_boxes,
                                                   const float* __restrict__ img_sz,
                                                   const float* __restrict__ costT_all,
                                                   float* __restrict__ lists) {
    const int tid = threadIdx.x;
    const int wid = tid >> 6, lane = tid & 63;

    if (blockIdx.x < 400) {
        int w = blockIdx.x * 4 + wid;
        int b = w / NG, g = w - b * NG;
        const float* col = costT_all + (size_t)b * NQ * NG + (size_t)g * NQ;

        float va[8]; int ia[8];
#pragma unroll
        for (int j = 0; j < 8; ++j) { va[j] = INFINITY; ia[j] = QINF; }
        for (int q = lane; q < NQ; q += 64) {
            float v = col[q];
            INS8(va, ia, v, q);
        }
        MERGE8(va, ia);
        if (lane == 0) {
            float* o = lists + (size_t)w * LSTRIDE;
            o[1] = (float)ia[0]; o[2] = (float)ia[1]; o[3] = (float)ia[2]; o[4] = (float)ia[3];
            o[5] = (float)ia[4]; o[6] = (float)ia[5]; o[7] = (float)ia[6]; o[8] = (float)ia[7];
        }
        return;
    }

    int w = (blockIdx.x - 400) * 4 + wid;
    dynk_wave(w, lane, pred_boxes, gt_boxes, img_sz, lists);
}

// =================== K3: match_main — prologue + while-loop, dump state to ws ===================
__global__ __launch_bounds__(K3_BS) void match_main(const float* __restrict__ lists,
                                                    const float* __restrict__ rowamin_all,
                                                    const float* __restrict__ costT_all,
                                                    char* __restrict__ ws) {
    const int b = blockIdx.x;
    const int tid = threadIdx.x;
    const int wave = tid >> 6;
    const int lane = tid & 63;

    __shared__ uint32_t Mw[4][NQ];         // 32 KB (plane layout)
    __shared__ float crow[MAXC][NG + 1];   // 38.8 KB
    __shared__ int m_it[NQ];               // 8 KB
    __shared__ int16_t c16[NQ];            // 4 KB
    __shared__ int16_t cand[NG][NCAND];    // 1.6 KB
    __shared__ int crowq[MAXC];
    __shared__ int colcnt[NG];
    __shared__ int needscan[NG];
    __shared__ int touched[128];
    __shared__ int nconf0, nscan, ntq, persist;

    uint32_t* MwG = (uint32_t*)(ws + WS_MW) + (size_t)b * 4 * NQ;
    int16_t* mitG = (int16_t*)(ws + WS_MIT) + (size_t)b * NQ;
    int16_t* cidxG = (int16_t*)(ws + WS_CIDX) + (size_t)b * NQ;
    float* crowG = (float*)(ws + WS_CROW) + (size_t)b * MAXC * NG;
    int* scalG = (int*)(ws + WS_SCAL) + b * 8;
    const float* costT = costT_all + (size_t)b * NQ * NG;
    const float* rowamin_b = rowamin_all + b * NQ;

    if (tid == 0) { nconf0 = 0; nscan = 0; ntq = 0; persist = 0; }
    for (int q = tid; q < NQ; q += K3_BS) {
        Mw[0][q] = 0; Mw[1][q] = 0; Mw[2][q] = 0; Mw[3][q] = 0;
        c16[q] = -1; m_it[q] = QINF;
    }
    __syncthreads();

    if (tid < NG) {
        const float* o = lists + (size_t)(b * NG + tid) * LSTRIDE;
        int k = (int)o[0];
        int word = tid >> 5;
        uint32_t bit = 1u << (tid & 31);
        for (int j = 0; j < NCAND; ++j) {
            float f = o[1 + j];
            cand[tid][j] = (f >= 32767.0f) ? (int16_t)SQINF : (int16_t)(int)f;
        }
        for (int j = 0; j < 5; ++j)
            if (j < k) atomicOr(&Mw[word][(int)o[1 + j]], bit);
        colcnt[tid] = k;
    }
    __syncthreads();

    // conflict0 pass
    for (int q = tid; q < NQ; q += K3_BS) {
        uint32_t w0 = Mw[0][q], w1 = Mw[1][q], w2 = Mw[2][q], w3 = Mw[3][q];
        int pc = __popc(w0) + __popc(w1) + __popc(w2) + __popc(w3);
        if (pc > 1) {
            int slot = atomicAdd(&nconf0, 1);
            int c = (slot < MAXC) ? slot : -1;
            c16[q] = (c >= 0) ? (int16_t)c : (int16_t)-2;
            m_it[q] = -1;
            if (c >= 0) crowq[c] = q;
            int mg = (int)rowamin_b[q];
            uint32_t words[4] = {w0, w1, w2, w3};
            for (int w = 0; w < 4; ++w) {
                uint32_t word = words[w];
                while (word) {
                    int bp = __ffs(word) - 1;
                    word &= word - 1;
                    atomicSub(&colcnt[w * 32 + bp], 1);
                }
                Mw[w][q] = 0;
            }
            Mw[mg >> 5][q] = 1u << (mg & 31);
            atomicAdd(&colcnt[mg], 1);
        } else if (pc == 1) {
            m_it[q] = -1;
        }
    }
    __syncthreads();

    const int nc0 = nconf0;
    const int ncached = (nc0 < MAXC) ? nc0 : MAXC;
    const bool hasOvf = nc0 > MAXC;
    for (int i = tid; i < ncached * NG; i += K3_BS) {
        int c = i / NG, g = i - c * NG;
        crow[c][g] = costT[(size_t)g * NQ + crowq[c]];
    }
    __syncthreads();

    int unm = __syncthreads_or(tid < NG && colcnt[tid] == 0);
    int L = 0;

    for (int it = 0; it < MAX_ITERS; ++it) {
        if (!unm) break;
        L = it + 1;

        for (int i = tid; i < ncached * NG; i += K3_BS) {
            int c = i / NG, g = i - c * NG;
            crow[c][g] += 100000.0f;
        }
        if (tid < NG && colcnt[tid] == 0) {
            int g = tid;
            int win = -1;
            for (int j = 0; j < NCAND; ++j) {
                int qi = cand[g][j];
                if (qi != SQINF && m_it[qi] >= it) { win = qi; break; }
            }
            if (win >= 0) {
                atomicOr(&Mw[g >> 5][win], 1u << (g & 31));
                atomicMin(&m_it[win], it);
                colcnt[g] = 1;
                touched[atomicAdd(&ntq, 1)] = win;
            } else {
                needscan[atomicAdd(&nscan, 1)] = g;
            }
        }
        __syncthreads();  // B2

        int ns = nscan;
        if (ns > 0) {
            for (int s = wave; s < ns; s += NW3) {
                int g = needscan[s];
                const float* col = costT + (size_t)g * NQ;
                float mv = INFINITY; int mi = QINF;
                for (int q = lane; q < NQ; q += 64) {
                    if (m_it[q] >= it) {
                        float v = col[q];
                        if (v < mv || (v == mv && q < mi)) { mv = v; mi = q; }
                    }
                }
                for (int off = 1; off < 64; off <<= 1) {
                    float ov = __shfl_xor(mv, off); int oi = __shfl_xor(mi, off);
                    if (ov < mv || (ov == mv && oi < mi)) { mv = ov; mi = oi; }
                }
                if (mi == QINF) {
                    for (int q = lane; q < NQ; q += 64) {
                        int nq = it - m_it[q]; if (nq < 0) nq = 0;
                        float v = fmut(col[q], nq);
                        if (v < mv || (v == mv && q < mi)) { mv = v; mi = q; }
                    }
                    for (int off = 1; off < 64; off <<= 1) {
                        float ov = __shfl_xor(mv, off); int oi = __shfl_xor(mi, off);
                        if (ov < mv || (ov == mv && oi < mi)) { mv = ov; mi = oi; }
                    }
                }
                if (lane == 0) {
                    atomicOr(&Mw[g >> 5][mi], 1u << (g & 31));
                    atomicMin(&m_it[mi], it);
                    colcnt[g] = 1;
                    touched[atomicAdd(&ntq, 1)] = mi;
                }
            }
            __syncthreads();  // B2b
        }

        int myconf = (tid == 0 && persist) ? 1 : 0;
        int nt = ntq;
        for (int s = tid; s < nt; s += K3_BS) {
            int q = touched[s];
            int pc = __popc(Mw[0][q]) + __popc(Mw[1][q]) + __popc(Mw[2][q]) + __popc(Mw[3][q]);
            if (pc > 1) {
                myconf = 1;
                if (c16[q] == -1) persist = 1;
            }
        }
        int hc = __syncthreads_or(myconf);
        if (!hc) break;

        if (tid == 0) { ntq = 0; nscan = 0; }
        for (int c = tid; c < ncached; c += K3_BS) {
            int q = crowq[c];
            float mv = crow[c][0]; int mg = 0;
            for (int g = 1; g < NG; ++g) { float v = crow[c][g]; if (v < mv) { mv = v; mg = g; } }
            int keepw = mg >> 5;
            uint32_t keepb = 1u << (mg & 31);
            for (int w = 0; w < 4; ++w) {
                uint32_t word = Mw[w][q];
                uint32_t keep = (w == keepw) ? keepb : 0u;
                uint32_t toclear = word & ~keep;
                while (toclear) {
                    int bp = __ffs(toclear) - 1;
                    toclear &= toclear - 1;
                    atomicSub(&colcnt[w * 32 + bp], 1);
                }
                if (keep && !(word & keep)) atomicAdd(&colcnt[mg], 1);
                Mw[w][q] = keep;
            }
        }
        if (hasOvf) {
            for (int q = tid; q < NQ; q += K3_BS) {
                if (c16[q] != -2) continue;
                int k = it + 1;
                float mv = fmut(costT[q], k); int mg = 0;
                for (int g = 1; g < NG; ++g) {
                    float v = fmut(costT[(size_t)g * NQ + q], k);
                    if (v < mv) { mv = v; mg = g; }
                }
                int keepw = mg >> 5;
                uint32_t keepb = 1u << (mg & 31);
                for (int w = 0; w < 4; ++w) {
                    uint32_t word = Mw[w][q];
                    uint32_t keep = (w == keepw) ? keepb : 0u;
                    uint32_t toclear = word & ~keep;
                    while (toclear) {
                        int bp = __ffs(toclear) - 1;
                        toclear &= toclear - 1;
                        atomicSub(&colcnt[w * 32 + bp], 1);
                    }
                    if (keep && !(word & keep)) atomicAdd(&colcnt[mg], 1);
                    Mw[w][q] = keep;
                }
            }
        }
        __syncthreads();  // B3
        unm = __syncthreads_or(tid < NG && colcnt[tid] == 0);
    }

    // dump state
    uint32_t* MwF = &Mw[0][0];
    for (int i = tid; i < 4 * NQ; i += K3_BS) MwG[i] = MwF[i];
    for (int q = tid; q < NQ; q += K3_BS) {
        int v = m_it[q];
        mitG[q] = (v > 32000) ? (int16_t)SQINF : (int16_t)v;
        cidxG[q] = c16[q];
    }
    for (int i = tid; i < ncached * NG; i += K3_BS) crowG[i] = crow[i / NG][i - (i / NG) * NG];
    if (tid == 0) { scalG[0] = nc0; scalG[1] = L; }
}

// =================== K4: finish_ex — matched_qid | sel/gti | M expand (cost in ws: no aliasing) ===================
__global__ __launch_bounds__(256) void finish_ex(const char* __restrict__ ws,
                                                 const float* __restrict__ costT_all,
                                                 float* __restrict__ out) {
    const int tid = threadIdx.x;
    const int blk = blockIdx.x;

    if (blk < 400) {
        int w = blk * 4 + (tid >> 6);
        int lane = tid & 63;
        int b = w / NG, g = w - b * NG;
        const int* scalG = (const int*)(ws + WS_SCAL) + b * 8;
        const int L = scalG[1];
        const uint32_t* MwP = (const uint32_t*)(ws + WS_MW) + (size_t)b * 4 * NQ + (size_t)(g >> 5) * NQ;
        const int16_t* mitG = (const int16_t*)(ws + WS_MIT) + (size_t)b * NQ;
        const int16_t* cidxG = (const int16_t*)(ws + WS_CIDX) + (size_t)b * NQ;
        const float* crowG = (const float*)(ws + WS_CROW) + (size_t)b * MAXC * NG;
        const float* col = costT_all + (size_t)b * NQ * NG + (size_t)g * NQ;
        const uint32_t bit = 1u << (g & 31);

        float mv = INFINITY; int mi = QINF;
        for (int q = lane; q < NQ; q += 64) {
            float v = 1e30f;
            if (MwP[q] & bit) {
                int c = cidxG[q];
                if (c >= 0) v = crowG[c * NG + g];
                else {
                    int m = mitG[q];
                    int nq = (m == SQINF) ? 0 : (L - 1 - m);
                    if (nq < 0) nq = 0;
                    v = fmut(col[q], nq);
                }
            }
            if (v < mv || (v == mv && q < mi)) { mv = v; mi = q; }
        }
        for (int off = 1; off < 64; off <<= 1) {
            float ov = __shfl_xor(mv, off); int oi = __shfl_xor(mi, off);
            if (ov < mv || (ov == mv && oi < mi)) { mv = ov; mi = oi; }
        }
        if (lane == 0) out[OFF_MQ + b * NG + g] = (float)mi;
        return;
    }

    if (blk < 525) {
        int idx = (blk - 400) * 256 + tid;
        if (idx < BATCH * NQ) {
            int b = idx / NQ, q = idx - b * NQ;
            const uint32_t* MwG = (const uint32_t*)(ws + WS_MW) + (size_t)b * 4 * NQ;
            uint32_t w0 = MwG[q], w1 = MwG[NQ + q], w2 = MwG[2 * NQ + q], w3 = MwG[3 * NQ + q];
            out[OFF_SEL + idx] = (w0 | w1 | w2 | w3) ? 1.0f : 0.0f;
            int gi = 0;
            if (w0) gi = __ffs(w0) - 1;
            else if (w1) gi = 32 + __ffs(w1) - 1;
            else if (w2) gi = 64 + __ffs(w2) - 1;
            else if (w3) gi = 96 + __ffs(w3) - 1;
            out[OFF_GTI + idx] = (float)gi;
        }
        return;
    }

    const int e = blk - 525;
    const int b = e >> 3, j = e & 7;
    const int q0 = j * 250;
    __shared__ uint32_t msk[4][256];
    const uint32_t* MwG = (const uint32_t*)(ws + WS_MW) + (size_t)b * 4 * NQ;
    for (int i = tid; i < 1000; i += 256) {
        int w = i / 250, q = i - w * 250;
        msk[w][q] = MwG[w * NQ + q0 + q];
    }
    __syncthreads();
    float4* dst = reinterpret_cast<float4*>(out + OFF_M + (size_t)b * NQ * NG + (size_t)q0 * NG);
    for (int i = tid; i < 6250; i += 256) {
        int flat = i * 4;
        int ql = flat / NG;
        int g0 = flat - ql * NG;
        uint32_t w = msk[g0 >> 5][ql];
        int sh = g0 & 31;
        float4 v;
        v.x = ((w >> sh) & 1) ? 1.0f : 0.0f;
        v.y = ((w >> (sh + 1)) & 1) ? 1.0f : 0.0f;
        v.z = ((w >> (sh + 2)) & 1) ? 1.0f : 0.0f;
        v.w = ((w >> (sh + 3)) & 1) ? 1.0f : 0.0f;
        dst[i] = v;
    }
}

// =================== fallback: monolithic match (cost in out+OFF_M; small-ws path) ===================
__global__ __launch_bounds__(K3_BS) void match_mono(const float* __restrict__ lists,
                                                    float* __restrict__ out) {
    const int b = blockIdx.x;
    const int tid = threadIdx.x;
    const int wave = tid >> 6;
    const int lane = tid & 63;

    __shared__ uint32_t Msh[NQ][4];
    __shared__ float crow[MAXC][NG + 1];
    __shared__ int m_it[NQ];
    __shared__ int16_t cidx[NQ];
    __shared__ int candq[NG][NCAND];
    __shared__ int crowq[MAXC];
    __shared__ int colcnt[NG];
    __shared__ int needscan[NG];
    __shared__ int touched[128];
    __shared__ int nconf0, nscan, ntq, persist;

    float* costT = out + OFF_M + (size_t)b * NQ * NG;
    float* selOut = out + OFF_SEL + b * NQ;
    float* gtiOut = out + OFF_GTI + b * NQ;
    const float* rowamin_b = out + OFF_GTI + b * NQ;
    float* mqOut = out + OFF_MQ + b * NG;

    if (tid == 0) { nconf0 = 0; nscan = 0; ntq = 0; persist = 0; }
    for (int q = tid; q < NQ; q += K3_BS) {
        Msh[q][0] = 0; Msh[q][1] = 0; Msh[q][2] = 0; Msh[q][3] = 0;
        cidx[q] = -1; m_it[q] = QINF;
    }
    __syncthreads();
    if (tid < NG) {
        const float* o = lists + (size_t)(b * NG + tid) * LSTRIDE;
        int k = (int)o[0];
        int word = tid >> 5;
        uint32_t bit = 1u << (tid & 31);
        for (int j = 0; j < NCAND; ++j) candq[tid][j] = (int)o[1 + j];
        for (int j = 0; j < 5; ++j)
            if (j < k) atomicOr(&Msh[candq[tid][j]][word], bit);
        colcnt[tid] = k;
    }
    __syncthreads();
    for (int q = tid; q < NQ; q += K3_BS) {
        uint4 m = *reinterpret_cast<const uint4*>(&Msh[q][0]);
        int pc = __popc(m.x) + __popc(m.y) + __popc(m.z) + __popc(m.w);
        if (pc > 1) {
            int slot = atomicAdd(&nconf0, 1);
            int c = (slot < MAXC) ? slot : -1;
            cidx[q] = (c >= 0) ? (int16_t)c : (int16_t)-2;
            m_it[q] = -1;
            if (c >= 0) crowq[c] = q;
            int mg = (int)rowamin_b[q];
            uint32_t words[4] = {m.x, m.y, m.z, m.w};
            for (int w = 0; w < 4; ++w) {
                uint32_t word = words[w];
                while (word) {
                    int bp = __ffs(word) - 1;
                    word &= word - 1;
                    atomicSub(&colcnt[w * 32 + bp], 1);
                }
                Msh[q][w] = 0;
            }
            Msh[q][mg >> 5] = 1u << (mg & 31);
            atomicAdd(&colcnt[mg], 1);
        } else if (pc == 1) {
            m_it[q] = -1;
        }
    }
    __syncthreads();
    const int ncached = (nconf0 < MAXC) ? nconf0 : MAXC;
    const bool hasOvf = nconf0 > MAXC;
    for (int i = tid; i < ncached * NG; i += K3_BS) {
        int c = i / NG, g = i - c * NG;
        crow[c][g] = costT[(size_t)g * NQ + crowq[c]];
    }
    __syncthreads();
    int unm = __syncthreads_or(tid < NG && colcnt[tid] == 0);
    int L = 0;
    for (int it = 0; it < MAX_ITERS; ++it) {
        if (!unm) break;
        L = it + 1;
        for (int i = tid; i < ncached * NG; i += K3_BS) {
            int c = i / NG, g = i - c * NG;
            crow[c][g] += 100000.0f;
        }
        if (tid < NG && colcnt[tid] == 0) {
            int g = tid;
            int win = -1;
            for (int j = 0; j < NCAND; ++j) {
                int qi = candq[g][j];
                if (qi != QINF && m_it[qi] >= it) { win = qi; break; }
            }
            if (win >= 0) {
                atomicOr(&Msh[win][g >> 5], 1u << (g & 31));
                atomicMin(&m_it[win], it);
                colcnt[g] = 1;
                touched[atomicAdd(&ntq, 1)] = win;
            } else {
                needscan[atomicAdd(&nscan, 1)] = g;
            }
        }
        __syncthreads();
        int ns = nscan;
        if (ns > 0) {
            for (int s = wave; s < ns; s += NW3) {
                int g = needscan[s];
                const float* col = costT + (size_t)g * NQ;
                float mv = INFINITY; int mi = QINF;
                for (int q = lane; q < NQ; q += 64) {
                    if (m_it[q] >= it) {
                        float v = col[q];
                        if (v < mv || (v == mv && q < mi)) { mv = v; mi = q; }
                    }
                }
                for (int off = 1; off < 64; off <<= 1) {
                    float ov = __shfl_xor(mv, off); int oi = __shfl_xor(mi, off);
                    if (ov < mv || (ov == mv && oi < mi)) { mv = ov; mi = oi; }
                }
                if (mi == QINF) {
                    for (int q = lane; q < NQ; q += 64) {
                        int nq = it - m_it[q]; if (nq < 0) nq = 0;
                        float v = fmut(col[q], nq);
                        if (v < mv || (v == mv && q < mi)) { mv = v; mi = q; }
                    }
                    for (int off = 1; off < 64; off <<= 1) {
                        float ov = __shfl_xor(mv, off); int oi = __shfl_xor(mi, off);
                        if (ov < mv || (ov == mv && oi < mi)) { mv = ov; mi = oi; }
                    }
                }
                if (lane == 0) {
                    atomicOr(&Msh[mi][g >> 5], 1u << (g & 31));
                    atomicMin(&m_it[mi], it);
                    colcnt[g] = 1;
                    touched[atomicAdd(&ntq, 1)] = mi;
                }
            }
            __syncthreads();
        }
        int myconf = (tid == 0 && persist) ? 1 : 0;
        int nt = ntq;
        for (int s = tid; s < nt; s += K3_BS) {
            int q = touched[s];
            uint4 m = *reinterpret_cast<const uint4*>(&Msh[q][0]);
            int pc = __popc(m.x) + __popc(m.y) + __popc(m.z) + __popc(m.w);
            if (pc > 1) {
                myconf = 1;
                if (cidx[q] == -1) persist = 1;
            }
        }
        int hc = __syncthreads_or(myconf);
        if (!hc) break;
        if (tid == 0) { ntq = 0; nscan = 0; }
        for (int c = tid; c < ncached; c += K3_BS) {
            int q = crowq[c];
            float mv = crow[c][0]; int mg = 0;
            for (int g = 1; g < NG; ++g) { float v = crow[c][g]; if (v < mv) { mv = v; mg = g; } }
            int keepw = mg >> 5;
            uint32_t keepb = 1u << (mg & 31);
            for (int w = 0; w < 4; ++w) {
                uint32_t word = Msh[q][w];
                uint32_t keep = (w == keepw) ? keepb : 0u;
                uint32_t toclear = word & ~keep;
                while (toclear) {
                    int bp = __ffs(toclear) - 1;
                    toclear &= toclear - 1;
                    atomicSub(&colcnt[w * 32 + bp], 1);
                }
                if (keep && !(word & keep)) atomicAdd(&colcnt[mg], 1);
                Msh[q][w] = keep;
            }
        }
        if (hasOvf) {
            for (int q = tid; q < NQ; q += K3_BS) {
                if (cidx[q] != -2) continue;
                int k = it + 1;
                float mv = fmut(costT[q], k); int mg = 0;
                for (int g = 1; g < NG; ++g) {
                    float v = fmut(costT[(size_t)g * NQ + q], k);
                    if (v < mv) { mv = v; mg = g; }
                }
                int keepw = mg >> 5;
                uint32_t keepb = 1u << (mg & 31);
                for (int w = 0; w < 4; ++w) {
                    uint32_t word = Msh[q][w];
                    uint32_t keep = (w == keepw) ? keepb : 0u;
                    uint32_t toclear = word & ~keep;
                    while (toclear) {
                        int bp = __ffs(toclear) - 1;
                        toclear &= toclear - 1;
                        atomicSub(&colcnt[w * 32 + bp], 1);
                    }
                    if (keep && !(word & keep)) atomicAdd(&colcnt[mg], 1);
                    Msh[q][w] = keep;
                }
            }
        }
        __syncthreads();
        unm = __syncthreads_or(tid < NG && colcnt[tid] == 0);
    }
    for (int g = wave; g < NG; g += NW3) {
        int word = g >> 5;
        uint32_t bit = 1u << (g & 31);
        const float* col = costT + (size_t)g * NQ;
        float mv = INFINITY; int mi = QINF;
        for (int q = lane; q < NQ; q += 64) {
            float v = 1e30f;
            if (Msh[q][word] & bit) {
                int c = cidx[q];
                if (c >= 0) v = crow[c][g];
                else {
                    int nq = L - 1 - m_it[q]; if (nq < 0) nq = 0;
                    v = fmut(col[q], nq);
                }
            }
            if (v < mv || (v == mv && q < mi)) { mv = v; mi = q; }
        }
        for (int off = 1; off < 64; off <<= 1) {
            float ov = __shfl_xor(mv, off); int oi = __shfl_xor(mi, off);
            if (ov < mv || (ov == mv && oi < mi)) { mv = ov; mi = oi; }
        }
        if (lane == 0) mqOut[g] = (float)mi;
    }
    for (int q = tid; q < NQ; q += K3_BS) {
        uint4 m = *reinterpret_cast<const uint4*>(&Msh[q][0]);
        selOut[q] = (m.x | m.y | m.z | m.w) ? 1.0f : 0.0f;
        int gi = 0;
        if (m.x) gi = __ffs(m.x) - 1;
        else if (m.y) gi = 32 + __ffs(m.y) - 1;
        else if (m.z) gi = 64 + __ffs(m.z) - 1;
        else if (m.w) gi = 96 + __ffs(m.w) - 1;
        gtiOut[q] = (float)gi;
    }
    __syncthreads();
    for (int i = tid; i < NQ * NG; i += K3_BS) {
        int q = i / NG;
        int g = i - q * NG;
        costT[i] = (Msh[q][g >> 5] & (1u << (g & 31))) ? 1.0f : 0.0f;
    }
}

extern "C" void kernel_launch(void* const* d_in, const int* in_sizes, int n_in,
                              void* d_out, int out_size, void* d_ws, size_t ws_size,
                              hipStream_t stream) {
    const float* logits = (const float*)d_in[0];
    const float* pboxes = (const float*)d_in[1];
    const float* gboxes = (const float*)d_in[2];
    const int* labels = (const int*)d_in[3];
    const float* img = (const float*)d_in[4];
    float* out = (float*)d_out;
    char* ws = (char*)d_ws;

    if (ws_size >= (size_t)WS_NEED) {
        float* costT = (float*)(ws + WS_COST);
        float* lists = (float*)(ws + WS_LISTS);
        // K1: cost tiles + overlapped taskB (dyn_k)
        fgcost_kernel<<<K1_BLOCKS, 256, 0, stream>>>(logits, pboxes, gboxes, labels, img,
                                                     costT, out + OFF_GTI, lists);
        // K2: taskA bottom-8 per column (wide)
        init_kernel<<<400, 256, 0, stream>>>(pboxes, gboxes, img, costT, lists);
        // K3: serial matching loop (16 blocks)
        match_main<<<BATCH, K3_BS, 0, stream>>>(lists, out + OFF_GTI, costT, ws);
        // K4: wide epilogue + M expand (cost in ws -> no aliasing)
        finish_ex<<<653, 256, 0, stream>>>(ws, costT, out);
    } else {
        float* lists = (float*)ws;  // 57.6 KB
        fgcost_kernel<<<K1_TILEB, 256, 0, stream>>>(logits, pboxes, gboxes, labels, img,
                                                    out + OFF_M, out + OFF_GTI, lists);
        init_kernel<<<800, 256, 0, stream>>>(pboxes, gboxes, img, out + OFF_M, lists);
        match_mono<<<BATCH, K3_BS, 0, stream>>>(lists, out);
    }
}